// Round 4
// baseline (178.218 us; speedup 1.0000x reference)
//
#include <hip/hip_runtime.h>
#include <cstdint>

#define KDIM 128
#define BATCH 131072
#define LDH 136    // bf16 LDS row stride: 272 B/row keeps 16B alignment, spreads banks

typedef __attribute__((ext_vector_type(8))) short short8x;          // MFMA A/B frag
typedef __attribute__((ext_vector_type(4))) float float4x;          // MFMA C/D frag
typedef __attribute__((ext_vector_type(4))) unsigned int uint4x;

#define MFMA16(a, b, c) __builtin_amdgcn_mfma_f32_16x16x32_bf16((a), (b), (c), 0, 0, 0)

// pack two fp32 -> bf16x2 dword, round-half-up
__device__ __forceinline__ unsigned int pk_bf16(float a, float b) {
    unsigned int ua = __float_as_uint(a) + 0x8000u;
    unsigned int ub = __float_as_uint(b) + 0x8000u;
    return __builtin_amdgcn_perm(ub, ua, 0x07060302u);  // {hi16(b), hi16(a)}
}

__device__ __forceinline__ unsigned short f2bf(float f) {   // RNE (prep kernel)
    unsigned int u = __float_as_uint(f);
    u += 0x7FFFu + ((u >> 16) & 1u);
    return (unsigned short)(u >> 16);
}

// clamped Pade tanh, err<=0.025 abs; attenuated ~0.05x into y. No transcendental.
__device__ __forceinline__ float tanh_pade(float v) {
    float z  = fminf(fmaxf(v, -4.0f), 4.0f);
    float z2 = z * z;
    float num = z * (27.0f + z2);
    float den = fmaf(z2, 9.0f, 27.0f);
    return num * __frcp_rn(den);
}

// W[k][n] fp32 -> Wt[n][k] bf16
__global__ void prep_weights(const float* __restrict__ W1, const float* __restrict__ W2,
                             unsigned short* __restrict__ W1t, unsigned short* __restrict__ W2t) {
    int idx = blockIdx.x * 256 + threadIdx.x;
    int n = idx & 127, k = idx >> 7;
    W1t[n * 128 + k] = f2bf(W1[idx]);
    W2t[n * 128 + k] = f2bf(W2[idx]);
}

// Software-pipelined, wave-private. 2048 waves x (2 tiles of 32 rows).
// Operands swapped (A=W^T, B=X^T): lane(l15,quad) owns batch rows {l15,l15+16},
// output cols nt*16+quad*4+reg -> mu/om pairs in-lane.
__global__ __launch_bounds__(256, 2) void koopman_main(
        const float* __restrict__ x, const float* __restrict__ b1,
        const float* __restrict__ b2, const unsigned short* __restrict__ W1t,
        const unsigned short* __restrict__ W2t, float* __restrict__ y) {
    __shared__ __align__(16) unsigned short Hall[4 * 32 * LDH];   // 34816 B (2 blocks/CU resident)

    const int tid  = threadIdx.x;
    const int lane = tid & 63;
    const int wave = tid >> 6;
    const int l15  = lane & 15;
    const int quad = lane >> 4;
    unsigned short* Hbf = Hall + wave * (32 * LDH);

    const size_t base = ((size_t)blockIdx.x * 4 + wave) * 64;   // 64 rows per wave

    float4  raw[16];
    short8x xf[2][4];

    // ---- tile-0 x load + bf16 pack ----
    #pragma unroll
    for (int h = 0; h < 2; ++h) {
        const float* xrow = x + (base + 16 * h + l15) * KDIM + quad * 8;
        #pragma unroll
        for (int ks = 0; ks < 4; ++ks) {
            raw[h * 8 + 2 * ks]     = *(const float4*)(xrow + ks * 32);
            raw[h * 8 + 2 * ks + 1] = *(const float4*)(xrow + ks * 32 + 4);
        }
    }
    #pragma unroll
    for (int h = 0; h < 2; ++h)
        #pragma unroll
        for (int ks = 0; ks < 4; ++ks) {
            float4 v0 = raw[h * 8 + 2 * ks], v1 = raw[h * 8 + 2 * ks + 1];
            uint4x u;
            u[0] = pk_bf16(v0.x, v0.y);
            u[1] = pk_bf16(v0.z, v0.w);
            u[2] = pk_bf16(v1.x, v1.y);
            u[3] = pk_bf16(v1.z, v1.w);
            xf[h][ks] = __builtin_bit_cast(short8x, u);
        }

    #pragma unroll
    for (int t = 0; t < 2; ++t) {
        const size_t rb = base + t * 32;

        // ---- matmul 1: register-double-buffered W1 frags ----
        float4x acc[2][8];
        #pragma unroll
        for (int h = 0; h < 2; ++h)
            #pragma unroll
            for (int nt = 0; nt < 8; ++nt) acc[h][nt] = (float4x){0.f, 0.f, 0.f, 0.f};
        {
            short8x wb[8], wn[8];
            #pragma unroll
            for (int nt = 0; nt < 8; ++nt)
                wb[nt] = *(const short8x*)&W1t[(nt * 16 + l15) * 128 + quad * 8];
            #pragma unroll
            for (int ks = 0; ks < 4; ++ks) {
                if (ks < 3) {
                    #pragma unroll
                    for (int nt = 0; nt < 8; ++nt)
                        wn[nt] = *(const short8x*)&W1t[(nt * 16 + l15) * 128 + (ks + 1) * 32 + quad * 8];
                }
                #pragma unroll
                for (int nt = 0; nt < 8; ++nt) {
                    acc[0][nt] = MFMA16(wb[nt], xf[0][ks], acc[0][nt]);
                    acc[1][nt] = MFMA16(wb[nt], xf[1][ks], acc[1][nt]);
                }
                if (ks < 3) {
                    #pragma unroll
                    for (int nt = 0; nt < 8; ++nt) wb[nt] = wn[nt];
                }
            }
        }

        // ---- bias + tanh -> packed b64 LDS writes ----
        #pragma unroll
        for (int nt = 0; nt < 8; ++nt) {
            float4 bb = *(const float4*)&b1[nt * 16 + quad * 4];
            #pragma unroll
            for (int h = 0; h < 2; ++h) {
                float4x v = acc[h][nt];
                uint2 d;
                d.x = pk_bf16(tanh_pade(v[0] + bb.x), tanh_pade(v[1] + bb.y));
                d.y = pk_bf16(tanh_pade(v[2] + bb.z), tanh_pade(v[3] + bb.w));
                *(uint2*)&Hbf[(16 * h + l15) * LDH + nt * 16 + quad * 4] = d;
            }
        }

        // ---- issue epilogue x re-reads now (in flight during matmul 2; L2-warm) ----
        float4 xe[2][8];
        #pragma unroll
        for (int h = 0; h < 2; ++h) {
            const float* xrow = x + (rb + 16 * h + l15) * KDIM + quad * 4;
            #pragma unroll
            for (int nt = 0; nt < 8; ++nt)
                xe[h][nt] = *(const float4*)(xrow + nt * 16);
        }

        // ---- matmul 2: register-double-buffered W2 frags, H from wave-private LDS ----
        float4x acc2[2][8];
        #pragma unroll
        for (int h = 0; h < 2; ++h)
            #pragma unroll
            for (int nt = 0; nt < 8; ++nt) acc2[h][nt] = (float4x){0.f, 0.f, 0.f, 0.f};
        {
            short8x wb[8], wn[8];
            #pragma unroll
            for (int nt = 0; nt < 8; ++nt)
                wb[nt] = *(const short8x*)&W2t[(nt * 16 + l15) * 128 + quad * 8];
            #pragma unroll
            for (int ks = 0; ks < 4; ++ks) {
                short8x hf0 = *(const short8x*)&Hbf[l15 * LDH + ks * 32 + quad * 8];
                short8x hf1 = *(const short8x*)&Hbf[(16 + l15) * LDH + ks * 32 + quad * 8];
                if (ks < 3) {
                    #pragma unroll
                    for (int nt = 0; nt < 8; ++nt)
                        wn[nt] = *(const short8x*)&W2t[(nt * 16 + l15) * 128 + (ks + 1) * 32 + quad * 8];
                }
                #pragma unroll
                for (int nt = 0; nt < 8; ++nt) {
                    acc2[0][nt] = MFMA16(wb[nt], hf0, acc2[0][nt]);
                    acc2[1][nt] = MFMA16(wb[nt], hf1, acc2[1][nt]);
                }
                if (ks < 3) {
                    #pragma unroll
                    for (int nt = 0; nt < 8; ++nt) wb[nt] = wn[nt];
                }
            }
        }

        // ---- prefetch next tile's x (in flight during epilogue compute) ----
        if (t == 0) {
            #pragma unroll
            for (int h = 0; h < 2; ++h) {
                const float* xrow = x + (base + 32 + 16 * h + l15) * KDIM + quad * 8;
                #pragma unroll
                for (int ks = 0; ks < 4; ++ks) {
                    raw[h * 8 + 2 * ks]     = *(const float4*)(xrow + ks * 32);
                    raw[h * 8 + 2 * ks + 1] = *(const float4*)(xrow + ks * 32 + 4);
                }
            }
        }

        // ---- epilogue: compute all 8 float4 per h, then store back-to-back (full lines) ----
        #pragma unroll
        for (int h = 0; h < 2; ++h) {
            float4 outv[8];
            #pragma unroll
            for (int nt = 0; nt < 8; ++nt) {
                float4 bv = *(const float4*)&b2[nt * 16 + quad * 4];
                float4 xv = xe[h][nt];
                float4x v = acc2[h][nt];
                float4 o;
                {
                    float tm = 0.01f * (v[0] + bv.x);
                    float tw = 0.01f * (v[1] + bv.y);
                    float tm2 = tm * tm, tw2 = tw * tw;
                    float ex = fmaf(tm2, fmaf(tm, 0.16666667f, 0.5f), 1.0f + tm);
                    float s  = tw * fmaf(tw2, -0.16666667f, 1.0f);
                    float c  = fmaf(tw2, -0.5f, 1.0f);
                    o.x = ex * fmaf(c, xv.x, -s * xv.y);
                    o.y = ex * fmaf(s, xv.x,  c * xv.y);
                }
                {
                    float tm = 0.01f * (v[2] + bv.z);
                    float tw = 0.01f * (v[3] + bv.w);
                    float tm2 = tm * tm, tw2 = tw * tw;
                    float ex = fmaf(tm2, fmaf(tm, 0.16666667f, 0.5f), 1.0f + tm);
                    float s  = tw * fmaf(tw2, -0.16666667f, 1.0f);
                    float c  = fmaf(tw2, -0.5f, 1.0f);
                    o.z = ex * fmaf(c, xv.z, -s * xv.w);
                    o.w = ex * fmaf(s, xv.z,  c * xv.w);
                }
                outv[nt] = o;
            }
            float* yrow = y + (rb + 16 * h + l15) * KDIM + quad * 4;
            #pragma unroll
            for (int nt = 0; nt < 8; ++nt)
                *(float4*)(yrow + nt * 16) = outv[nt];
        }

        // ---- pack next tile's frags ----
        if (t == 0) {
            #pragma unroll
            for (int h = 0; h < 2; ++h)
                #pragma unroll
                for (int ks = 0; ks < 4; ++ks) {
                    float4 v0 = raw[h * 8 + 2 * ks], v1 = raw[h * 8 + 2 * ks + 1];
                    uint4x u;
                    u[0] = pk_bf16(v0.x, v0.y);
                    u[1] = pk_bf16(v0.z, v0.w);
                    u[2] = pk_bf16(v1.x, v1.y);
                    u[3] = pk_bf16(v1.z, v1.w);
                    xf[h][ks] = __builtin_bit_cast(short8x, u);
                }
        }
    }
}

extern "C" void kernel_launch(void* const* d_in, const int* in_sizes, int n_in,
                              void* d_out, int out_size, void* d_ws, size_t ws_size,
                              hipStream_t stream) {
    const float* x  = (const float*)d_in[0];
    const float* W1 = (const float*)d_in[1];
    const float* b1 = (const float*)d_in[2];
    const float* W2 = (const float*)d_in[3];
    const float* b2 = (const float*)d_in[4];
    float* y = (float*)d_out;

    unsigned short* W1t = (unsigned short*)d_ws;
    unsigned short* W2t = W1t + 128 * 128;

    prep_weights<<<64, 256, 0, stream>>>(W1, W2, W1t, W2t);
    koopman_main<<<512, 256, 0, stream>>>(x, b1, b2, W1t, W2t, y);
}

// Round 6
// 160.701 us; speedup vs baseline: 1.1090x; 1.1090x over previous
//
#include <hip/hip_runtime.h>
#include <cstdint>

#define KDIM 128
#define BATCH 131072

// per-wave LDS region (bytes): max(H fp8 16*136=2176, pairs 16*264=4224) -> 4352 (16-mult)
#define WLS   4352
#define HSTR  136   // fp8 H row stride (bytes), 8-mult for b64 reads
#define PSTR  66    // pair-plane row stride (dwords), even -> b64-aligned

typedef __attribute__((ext_vector_type(4))) float float4v;
typedef __attribute__((ext_vector_type(4))) float float4x;   // MFMA C/D
typedef __attribute__((ext_vector_type(4))) unsigned int uint4v;
typedef __attribute__((ext_vector_type(2))) unsigned int uint2v;

#define MFMA8(a, b, c) __builtin_amdgcn_mfma_f32_16x16x32_fp8_fp8((a), (b), (c), 0, 0, 0)

// word-select must be an immediate -> template parameter
template<bool HI>
__device__ __forceinline__ unsigned int pk_fp8(float a, float b, unsigned int old) {
    return (unsigned int)__builtin_amdgcn_cvt_pk_fp8_f32(a, b, (int)old, HI);
}
// pack two fp32 -> bf16x2 dword (round-half-up): {lo16=bf(a), hi16=bf(b)}
__device__ __forceinline__ unsigned int pk_bf16(float a, float b) {
    unsigned int ua = __float_as_uint(a) + 0x8000u;
    unsigned int ub = __float_as_uint(b) + 0x8000u;
    return __builtin_amdgcn_perm(ub, ua, 0x07060302u);
}
__device__ __forceinline__ long mk64(unsigned int lo, unsigned int hi) {
    uint2v u; u[0] = lo; u[1] = hi;
    return __builtin_bit_cast(long, u);
}
// clamped Pade tanh, |err|<=0.025, attenuated ~0.05x into y
__device__ __forceinline__ float tanh_pade(float v) {
    float z  = fminf(fmaxf(v, -4.0f), 4.0f);
    float z2 = z * z;
    return (z * (27.0f + z2)) * __frcp_rn(fmaf(z2, 9.0f, 27.0f));
}

// W[k][n] fp32 -> fp8 SoA frag-order: byte addr ((nt*2+k0)*64 + lane)*16 + half*8 + j
// holds element A[m=nt*16+(lane&15)][k=(2*k0+half)*32 + (lane>>4)*8 + j]  (A = W^T)
__global__ void prep_weights(const float* __restrict__ W1, const float* __restrict__ W2,
                             unsigned int* __restrict__ W1q, unsigned int* __restrict__ W2q) {
    int d = blockIdx.x * 256 + threadIdx.x;      // 0..8191: two matrices x 4096 dwords
    const float* W = (d < 4096) ? W1 : W2;
    unsigned int* O = (d < 4096) ? W1q : W2q;
    int dd   = d & 4095;
    int frag = dd >> 2, q2 = dd & 3;
    int lane = frag & 63, ntk = frag >> 6;       // ntk = nt*2+k0
    int half = q2 >> 1,  j0 = (q2 & 1) * 4;
    int m  = (ntk >> 1) * 16 + (lane & 15);
    int ks = (ntk & 1) * 2 + half;
    int kb = ks * 32 + (lane >> 4) * 8 + j0;
    float f0 = W[(kb + 0) * 128 + m];
    float f1 = W[(kb + 1) * 128 + m];
    float f2 = W[(kb + 2) * 128 + m];
    float f3 = W[(kb + 3) * 128 + m];
    unsigned int r = pk_fp8<false>(f0, f1, 0u);
    r = pk_fp8<true>(f2, f3, r);
    O[dd] = r;
}

// M=16 rows/wave, 8192 waves, barrier-free wave-private. Swapped operands:
// A=W^T (m=hidden col), B=X^T (n=batch row) -> lane l15 owns batch row l15,
// hidden cols nt*16+quad*4+reg.
__global__ __launch_bounds__(256, 7) void koopman_main(
        const float* __restrict__ x, const float* __restrict__ b1,
        const float* __restrict__ b2, const unsigned int* __restrict__ W1q,
        const unsigned int* __restrict__ W2q, float* __restrict__ y) {
    __shared__ __align__(16) char smem[4 * WLS];

    const int tid  = threadIdx.x;
    const int lane = tid & 63;
    const int wave = tid >> 6;
    const int l15  = lane & 15;
    const int quad = lane >> 4;
    const int base = (blockIdx.x * 4 + wave) * 16;   // wave's 16 batch rows

    char* wls = smem + wave * WLS;
    unsigned char* Hq = (unsigned char*)wls;          // [16][HSTR] fp8   (phase A)
    unsigned int*  Pr = (unsigned int*)wls;           // [16][PSTR] pairs (phase B, aliases)

    // ---- x -> fp8 B-frags (nontemporal; row l15, cols quad*8+ks*32..+7) ----
    const float* xrow = x + (size_t)(base + l15) * KDIM + quad * 8;
    long xb[4];
    #pragma unroll
    for (int ks = 0; ks < 4; ++ks) {
        float4v a = __builtin_nontemporal_load((const float4v*)(xrow + ks * 32));
        float4v b = __builtin_nontemporal_load((const float4v*)(xrow + ks * 32 + 4));
        unsigned int lo = pk_fp8<false>(a[0], a[1], 0u);
        lo = pk_fp8<true>(a[2], a[3], lo);
        unsigned int hi = pk_fp8<false>(b[0], b[1], 0u);
        hi = pk_fp8<true>(b[2], b[3], hi);
        xb[ks] = mk64(lo, hi);
    }

    // ---- matmul 1: contiguous 16B weight loads, 2 MFMA each ----
    float4x acc[8];
    #pragma unroll
    for (int nt = 0; nt < 8; ++nt) acc[nt] = (float4x){0.f, 0.f, 0.f, 0.f};
    #pragma unroll
    for (int k0 = 0; k0 < 2; ++k0) {
        #pragma unroll
        for (int nt = 0; nt < 8; ++nt) {
            uint4v w = *(const uint4v*)&W1q[((nt * 2 + k0) * 64 + lane) * 4];
            acc[nt] = MFMA8(mk64(w[0], w[1]), xb[2 * k0],     acc[nt]);
            acc[nt] = MFMA8(mk64(w[2], w[3]), xb[2 * k0 + 1], acc[nt]);
        }
    }

    // ---- bias + tanh -> fp8 H in LDS (wave-private, DS in-order) ----
    #pragma unroll
    for (int nt = 0; nt < 8; ++nt) {
        float4v bb = *(const float4v*)&b1[nt * 16 + quad * 4];
        float t0 = tanh_pade(acc[nt][0] + bb[0]);
        float t1 = tanh_pade(acc[nt][1] + bb[1]);
        float t2 = tanh_pade(acc[nt][2] + bb[2]);
        float t3 = tanh_pade(acc[nt][3] + bb[3]);
        unsigned int dw = pk_fp8<false>(t0, t1, 0u);
        dw = pk_fp8<true>(t2, t3, dw);
        *(unsigned int*)&Hq[l15 * HSTR + nt * 16 + quad * 4] = dw;
    }

    // ---- matmul 2: H fp8 B-frags from LDS (b64), contiguous W2 loads ----
    long hb[4];
    #pragma unroll
    for (int ks = 0; ks < 4; ++ks)
        hb[ks] = *(const long*)&Hq[l15 * HSTR + ks * 32 + quad * 8];
    float4x acc2[8];
    #pragma unroll
    for (int nt = 0; nt < 8; ++nt) acc2[nt] = (float4x){0.f, 0.f, 0.f, 0.f};
    #pragma unroll
    for (int k0 = 0; k0 < 2; ++k0) {
        #pragma unroll
        for (int nt = 0; nt < 8; ++nt) {
            uint4v w = *(const uint4v*)&W2q[((nt * 2 + k0) * 64 + lane) * 4];
            acc2[nt] = MFMA8(mk64(w[0], w[1]), hb[2 * k0],     acc2[nt]);
            acc2[nt] = MFMA8(mk64(w[2], w[3]), hb[2 * k0 + 1], acc2[nt]);
        }
    }

    // ---- +b2, pair scale factors (ecm1=exp*cos-1, es=exp*sin) -> bf16x2 LDS plane ----
    // lane owns pairs j = nt*8 + quad*2 + {0,1} of row l15 (all H reads above are done;
    // Pr aliases Hq — same-wave DS ordering makes this safe without a barrier)
    #pragma unroll
    for (int nt = 0; nt < 8; ++nt) {
        float4v bv = *(const float4v*)&b2[nt * 16 + quad * 4];
        unsigned int pd[2];
        #pragma unroll
        for (int s = 0; s < 2; ++s) {
            float tm = 0.01f * (acc2[nt][2 * s]     + bv[2 * s]);
            float tw = 0.01f * (acc2[nt][2 * s + 1] + bv[2 * s + 1]);
            float tm2 = tm * tm, tw2 = tw * tw;
            float ex = fmaf(tm2, fmaf(tm, 0.16666667f, 0.5f), 1.0f + tm);
            float sn = tw * fmaf(tw2, -0.16666667f, 1.0f);
            float cs = fmaf(tw2, -0.5f, 1.0f);
            float ecm1 = fmaf(ex, cs, -1.0f);
            float es   = ex * sn;
            pd[s] = pk_bf16(ecm1, es);
        }
        *(uint2v*)&Pr[l15 * PSTR + nt * 8 + quad * 2] = (uint2v){pd[0], pd[1]};
    }

    // ---- epilogue: fully coalesced. float4 = 2 pairs; contiguous x read / y write ----
    const float4v* xg = (const float4v*)(x + (size_t)base * KDIM);
    float4v*       yg = (float4v*)(y + (size_t)base * KDIM);
    #pragma unroll
    for (int i = 0; i < 8; ++i) {
        int f = i * 64 + lane;            // float4 index: row = f>>5, pos = f&31
        int row = f >> 5, pos = f & 31;
        float4v xv = __builtin_nontemporal_load(xg + f);
        uint2v pd = *(const uint2v*)&Pr[row * PSTR + pos * 2];
        float4v o;
        {
            float ecm1 = __uint_as_float(pd[0] << 16);
            float es   = __uint_as_float(pd[0] & 0xFFFF0000u);
            float t = fmaf(ecm1, xv[0], xv[0]);
            o[0] = fmaf(-es, xv[1], t);
            float u = fmaf(ecm1, xv[1], xv[1]);
            o[1] = fmaf(es, xv[0], u);
        }
        {
            float ecm1 = __uint_as_float(pd[1] << 16);
            float es   = __uint_as_float(pd[1] & 0xFFFF0000u);
            float t = fmaf(ecm1, xv[2], xv[2]);
            o[2] = fmaf(-es, xv[3], t);
            float u = fmaf(ecm1, xv[3], xv[3]);
            o[3] = fmaf(es, xv[2], u);
        }
        __builtin_nontemporal_store(o, yg + f);
    }
}

extern "C" void kernel_launch(void* const* d_in, const int* in_sizes, int n_in,
                              void* d_out, int out_size, void* d_ws, size_t ws_size,
                              hipStream_t stream) {
    const float* x  = (const float*)d_in[0];
    const float* W1 = (const float*)d_in[1];
    const float* b1 = (const float*)d_in[2];
    const float* W2 = (const float*)d_in[3];
    const float* b2 = (const float*)d_in[4];
    float* y = (float*)d_out;

    unsigned int* W1q = (unsigned int*)d_ws;          // 16 KiB fp8 frag-order
    unsigned int* W2q = W1q + 4096;                   // 16 KiB

    prep_weights<<<32, 256, 0, stream>>>(W1, W2, W1q, W2q);
    koopman_main<<<BATCH / 64, 256, 0, stream>>>(x, b1, b2, W1q, W2q, y);
}